// Round 15
// baseline (125.895 us; speedup 1.0000x reference)
//
#include <hip/hip_runtime.h>

// RPN target generation for MI355X — 2-node pipeline: half-anchor-split main -> tiny finalize.
// Outputs (float32, concat): [0,A) rpn_match; [A,5A) rpn_bbox (A x 4); [5A] num_positives.
//
// Calibrated lessons (R2-R14):
//  * same-address device atomics ~100ns/op serialized per address -> depth O(64) max.
//  * DS queue in-order -> per-lane VGPR bitmask in hot loop + sparse post-loop LDS drain.
//  * per-block __threadfence() = L2 writeback on multi-XCD gfx950 -> cross-block
//    visibility ONLY via kernel boundaries (2 nodes).
//  * single-block latency-streaming trap -> finalize reads 64KB with 1024 thr.
//  * no memsets: biased keys beat 0xAA ws poison under atomicMax.
//  * R14: 2 threads/anchor (G-halves) doubled TLP (53% occ) at 86% VALU — but the
//    +128 half offset (2048 B = bank-aligned) made lane pairs collide on the same
//    bank quad: 6.56M conflict cycles (~10.7us/CU DS stall). R15: pad halves to
//    129-stride (odd-lane base bank quad +4) -> conflict-free broadcast pairs.
//
// ws layout: [0,A*8) akey | [+G*32*8) gkeyS | [+nb*4) pcount | [+nb*4) fvmin

#define GMAX 256
#define GPAD 129            // padded half stride: halves at s_gt[0..127] and s_gt[129..256]
#define SHARDS 32
#define KBIAS 0xC0000001u   // real key top-words >= 0xC0000002; 0xAAAAAAAA poison loses

// Faithful to the reference, including the intentional size "bug":
// gt_size = y2 + y1 (not y2 - y1); centre = 0.5 * (y1 + y2).
__device__ __forceinline__ float4 compute_deltas(float4 ab, float4 gb,
                                                 const float* __restrict__ sd) {
    float sy_g = gb.z + gb.x;   // box = (y1, x1, y2, x2) in (x,y,z,w)
    float sx_g = gb.w + gb.y;
    float sy_a = ab.z + ab.x;
    float sx_a = ab.w + ab.y;
    float4 d;
    d.x = (0.5f * (sy_g - sy_a) / sy_a) / sd[0];
    d.y = (0.5f * (sx_g - sx_a) / sx_a) / sd[1];
    d.z = logf(sy_g / sy_a) / sd[2];
    d.w = logf(sx_g / sx_a) / sd[3];
    return d;
}

__device__ __forceinline__ float iou_of(float4 ab, float a_area, float4 gb) {
    float y1 = fmaxf(ab.x, gb.x);
    float x1 = fmaxf(ab.y, gb.y);
    float y2 = fminf(ab.z, gb.z);
    float x2 = fminf(ab.w, gb.w);
    float inter = fmaxf(y2 - y1, 0.f) * fmaxf(x2 - x1, 0.f);
    float garea = (gb.z - gb.x) * (gb.w - gb.y);
    float uni = (a_area + garea) - inter;
    return inter * __builtin_amdgcn_rcpf(uni);   // exact 0 if inter==0
}

// padded LDS index: g in [0,128) -> g ; g in [128,256) -> g+1
__device__ __forceinline__ int pidx(int g) { return g + (g >> 7); }

// ---------- kernel 1: 2 threads/anchor (G split), outputs inline on even lane ----------
__global__ __launch_bounds__(256, 8) void rpn_main5(
    const float4* __restrict__ anchors,       // [A]
    const int* __restrict__ valid,            // [A] jnp bool as int32
    const int* __restrict__ cls,              // [G]
    const float4* __restrict__ gt,            // [G]
    const float* __restrict__ stdev,          // [4]
    float* __restrict__ out,                  // [5A+1]
    unsigned long long* __restrict__ akey,    // [A] plain stores (best_bits:32|bg:32)
    unsigned long long* __restrict__ gkeyS,   // [G*SHARDS] biased keys, poison-ok
    int* __restrict__ pcount,                 // [nb] plain stores
    int* __restrict__ fvmin,                  // [nb] plain stores (min valid ai, else INT_MAX)
    int A, int G)
{
    __shared__ float4 s_gt[GMAX + 2];         // padded: halves at 0 and GPAD
    __shared__ float s_area[GMAX + 2];
    __shared__ float s_crowdf[GMAX + 2];
    __shared__ unsigned long long s_key[GMAX]; // indexed by TRUE g
    __shared__ int s_anycrowd;
    __shared__ int s_cnt;
    __shared__ int s_fv;

    const int tid = threadIdx.x;
    if (tid == 0) { s_anycrowd = 0; s_cnt = 0; s_fv = 0x7FFFFFFF; }
    s_key[tid] = 0ULL;
    if (tid < G) {
        float4 b = gt[tid];
        const int pi = pidx(tid);
        s_gt[pi] = b;
        s_area[pi] = (b.z - b.x) * (b.w - b.y);
        int c = cls[tid];
        s_crowdf[pi] = (c < 0) ? 1.0f : 0.0f;
        if (c < 0) s_anycrowd = 1;            // benign race, same value
    }
    __syncthreads();
    const int any_crowd = s_anycrowd;

    // lane pair (2a, 2a+1) = anchor a, G-halves 0/1
    const int a  = tid >> 1;
    const int h  = tid & 1;
    const int ai = blockIdx.x * 128 + a;
    const bool ir = (ai < A);
    float4 ab = ir ? anchors[ai] : make_float4(0.f, 0.f, 1.f, 1.f);
    const bool v = ir && (valid[ai] != 0);
    const float a_area = (ab.z - ab.x) * (ab.w - ab.y);

    const int Gh = (G + 1) >> 1;
    const int g0 = h * Gh;
    const int gn = min(G - g0, Gh);           // may be < Gh for odd G

    float best;
    int bg = g0;
    float cm = 0.0f;
    unsigned long long mm0 = 0ULL, mm1 = 0ULL;

    if (!any_crowd && G == GMAX) {
        // ---- fast path: 128 gts/lane, inner 64 fully unrolled (const offsets+bits).
        // Lane-pair bases differ by GPAD*16 = 2064 B -> bank quads offset by 4:
        // the wave's two broadcast addresses never collide (R14's 6.56M conflicts).
        best = -1.0f;
        const float4* gp = &s_gt[h * GPAD];
        const float*  ap = &s_area[h * GPAD];
        for (int w = 0; w < 2; ++w) {
            unsigned long long m = 0ULL;
            const int base = w << 6;
            #pragma unroll
            for (int j = 0; j < 64; ++j) {
                const int gg = base + j;
                float4 gb = gp[gg];
                float y1 = fmaxf(ab.x, gb.x), x1 = fmaxf(ab.y, gb.y);
                float y2 = fminf(ab.z, gb.z), x2 = fminf(ab.w, gb.w);
                float inter = fmaxf(y2 - y1, 0.f) * fmaxf(x2 - x1, 0.f);
                float iou = inter * __builtin_amdgcn_rcpf((a_area + ap[gg]) - inter);
                if (iou > best) { best = iou; bg = g0 + gg; }   // first-index tie-break
                if (iou > 0.0f) m |= (1ULL << j);               // constant bit
            }
            if (w == 0) mm0 = m; else mm1 = m;
        }
    } else {
        // ---- general path: crowd / odd G (correctness-only) ----
        best = -2.0f;
        for (int gg = 0; gg < gn; ++gg) {
            const int g = g0 + gg;
            const int pi = pidx(g);
            float4 gb = s_gt[pi];
            float iou = iou_of(ab, a_area, gb);
            float cf = s_crowdf[pi];
            float eff = (cf != 0.0f) ? -1.0f : iou;
            if (eff > best) { best = eff; bg = g; }
            cm = fmaxf(cm, iou * cf);
            if (cf == 0.0f && iou > 0.0f) {
                if (gg < 64) mm0 |= (1ULL << gg); else mm1 |= (1ULL << (gg - 64));
            }
        }
    }

    // ---- merge the two halves via adjacent-lane shuffle (convergent) ----
    {
        float ob  = __shfl_xor(best, 1);
        int   obg = __shfl_xor(bg, 1);
        float ocm = __shfl_xor(cm, 1);
        if (h == 0) {
            // other half's g indices are all larger -> strict > keeps first-index ties
            if (ob > best) { best = ob; bg = obg; }
            cm = fmaxf(cm, ocm);
        }
    }

    bool no_crowd = any_crowd ? (cm < 0.001f) : true;
    bool pos = (best >= 0.7f);
    bool neg = (best < 0.3f) && no_crowd && !pos;
    bool posv = (h == 0) && pos && v;

    if (ir && h == 0) {
        out[ai] = v ? (pos ? 1.0f : (neg ? -1.0f : 0.0f)) : 0.0f;
        float4 d = make_float4(0.f, 0.f, 0.f, 0.f);
        if (pos && v) d = compute_deltas(ab, s_gt[pidx(bg)], stdev);
        ((float4*)(out + A))[ai] = d;
        akey[ai] = (((unsigned long long)__float_as_uint(best)) << 32) | (unsigned)bg;
    }

    // ---- sparse drain: each lane drains its OWN half's overlap bits ----
    if (v) {
        const unsigned lokey = ~(unsigned)ai;   // smaller ai -> larger lokey
        if (h == 0) atomicMin(&s_fv, ai);
        for (int w = 0; w < 2; ++w) {
            unsigned long long m = (w == 0) ? mm0 : mm1;
            while (m != 0ULL) {
                int j = __builtin_ctzll(m); m &= (m - 1ULL);
                int g = g0 + (w << 6) + j;
                float iou = iou_of(ab, a_area, s_gt[pidx(g)]);
                atomicMax(&s_key[g],
                    (((unsigned long long)(__float_as_uint(iou) + KBIAS)) << 32) | lokey);
            }
        }
    }

    unsigned long long bal = __ballot((int)posv);
    if ((tid & 63) == 0) atomicAdd(&s_cnt, (int)__popcll(bal));   // LDS only
    __syncthreads();

    // sharded global merge: 2046/32 = 64-deep per address (calibrated ok);
    // biased keys beat 0xAA poison -> no memset node.
    if (tid < G && s_key[tid] != 0ULL)
        atomicMax(&gkeyS[(size_t)tid * SHARDS + (blockIdx.x & (SHARDS - 1))],
                  s_key[tid]);
    if (tid == 0) { pcount[blockIdx.x] = s_cnt; fvmin[blockIdx.x] = s_fv; }
}

// ---------- kernel 2: single-block finalize (1024 thr, ~72 KB reads) ----------
__global__ __launch_bounds__(1024) void rpn_finalize2(
    const float4* __restrict__ anchors,
    const int* __restrict__ valid,
    const int* __restrict__ cls,
    const float4* __restrict__ gt,
    const float* __restrict__ stdev,
    float* __restrict__ out,
    const unsigned long long* __restrict__ akey,
    const unsigned long long* __restrict__ gkeyS,
    const int* __restrict__ pcount,
    const int* __restrict__ fvmin,
    int nb, int A, int G)
{
    __shared__ float4 s_gt[GMAX];
    __shared__ float s_crowdf[GMAX];
    __shared__ unsigned long long s_red[GMAX];   // per-gt max key
    __shared__ int s_tot[1024];
    __shared__ int s_fvt[1024];
    __shared__ int s_cnt;

    const int tid = threadIdx.x;
    if (tid == 0) s_cnt = 0;
    if (tid < GMAX) s_red[tid] = 0ULL;
    if (tid < G) {
        s_gt[tid] = gt[tid];
        s_crowdf[tid] = (cls[tid] < 0) ? 1.0f : 0.0f;
    }
    __syncthreads();

    // reduce shard matrix (G*SHARDS u64, coalesced) into s_red via LDS atomics
    const int total = G * SHARDS;
    for (int i = tid; i < total; i += 1024) {
        unsigned long long k = gkeyS[i];       // 0xAA poison loses to real biased keys
        atomicMax(&s_red[i / SHARDS], k);
    }

    // sum pcount, min fvmin (coalesced)
    int acc = 0, fv = 0x7FFFFFFF;
    for (int i = tid; i < nb; i += 1024) {
        acc += pcount[i];
        fv = min(fv, fvmin[i]);
    }
    s_tot[tid] = acc;
    s_fvt[tid] = fv;
    __syncthreads();
    for (int s = 512; s > 0; s >>= 1) {
        if (tid < s) {
            s_tot[tid] += s_tot[tid + s];
            s_fvt[tid] = min(s_fvt[tid], s_fvt[tid + s]);
        }
        __syncthreads();
    }
    const int first_valid = s_fvt[0];

    if (tid < G && s_crowdf[tid] == 0.0f) {    // scatter value is False for crowd gts
        unsigned long long key = s_red[tid];
        const bool has = ((unsigned)(key >> 32) >= (KBIAS + 1u));  // poison/empty -> none
        int w = -1;
        if (has) {
            w = (int)(~(unsigned)(key & 0xFFFFFFFFull));
        } else if (first_valid != 0x7FFFFFFF) {
            // no valid anchor overlapped this gt: column argmax = first valid anchor
            w = first_valid;
        }
        if (w >= 0) {
            float old = atomicExch(out + w, 1.0f);   // <=256 ops, mostly distinct addrs
            if (old != 1.0f) {
                // flipped to positive: deltas use the anchor's OWN argmax (akey[w])
                int bg = (int)(unsigned)akey[w];
                ((float4*)(out + A))[w] = compute_deltas(anchors[w], s_gt[bg], stdev);
                atomicAdd(&s_cnt, 1);
            }
        }
    }
    __syncthreads();
    if (tid == 0) out[(size_t)5 * A] = (float)(s_tot[0] + s_cnt);
}

// ---------------- fallback: monolithic kernel (used only if ws too small) ------
__global__ __launch_bounds__(256) void rpn_fused(
    const float4* __restrict__ anchors, const int* __restrict__ valid,
    const int* __restrict__ cls, const float4* __restrict__ gt,
    const float* __restrict__ stdev, float* __restrict__ out,
    unsigned long long* __restrict__ gkey, unsigned* __restrict__ done,
    int* __restrict__ cnt, int A, int G)
{
    __shared__ float4 s_gt[GMAX];
    __shared__ float s_crowdf[GMAX];
    __shared__ unsigned long long s_key[GMAX];
    __shared__ int s_anycrowd; __shared__ int s_cnt; __shared__ int s_islast;

    const int tid = threadIdx.x;
    if (tid == 0) { s_anycrowd = 0; s_cnt = 0; }
    if (tid < G) {
        s_gt[tid] = gt[tid];
        int c = cls[tid];
        s_crowdf[tid] = (c < 0) ? 1.0f : 0.0f;
        if (c < 0) s_anycrowd = 1;
        s_key[tid] = 0ULL;
    }
    __syncthreads();
    const int any_crowd = s_anycrowd;
    const int ai = blockIdx.x * 256 + tid;
    const bool in_range = (ai < A);
    float4 ab = in_range ? anchors[ai] : make_float4(0.f, 0.f, 1.f, 1.f);
    const bool v = in_range && (valid[ai] != 0);
    const float a_area = (ab.z - ab.x) * (ab.w - ab.y);
    const unsigned lokey = ~(unsigned)ai;

    float best = any_crowd ? -2.0f : -1.0f;
    int bg = 0; float crowd_max = 0.0f;
    unsigned long long ovmask[4];
    #pragma unroll
    for (int w = 0; w < 4; ++w) {
        unsigned long long m = 0ULL;
        #pragma unroll 4
        for (int j = 0; j < 64; ++j) {
            int g = (w << 6) + j;
            if (g >= G) break;
            float iou = iou_of(ab, a_area, s_gt[g]);
            float cf = s_crowdf[g];
            float eff = (any_crowd && cf != 0.0f) ? -1.0f : iou;
            if (eff > best) { best = eff; bg = g; }
            if (any_crowd) crowd_max = fmaxf(crowd_max, iou * cf);
            if (v && (cf == 0.0f) && iou > 0.0f) m |= (1ULL << j);
        }
        ovmask[w] = m;
    }
    #pragma unroll
    for (int w = 0; w < 4; ++w) {
        unsigned long long m = ovmask[w];
        while (m != 0ULL) {
            int j = __builtin_ctzll(m); m &= (m - 1ULL);
            int g = (w << 6) + j;
            float iou = iou_of(ab, a_area, s_gt[g]);
            atomicMax(&s_key[g],
                (((unsigned long long)(__float_as_uint(iou) + 1u)) << 32) | lokey);
        }
    }
    bool no_crowd = any_crowd ? (crowd_max < 0.001f) : true;
    bool pos = (best >= 0.7f);
    bool neg = (best < 0.3f) && no_crowd && !pos;
    unsigned long long pv = __ballot((int)(in_range && pos && v));
    if ((tid & 63) == 0) atomicAdd(&s_cnt, (int)__popcll(pv));
    if (in_range) {
        out[ai] = v ? (pos ? 1.0f : (neg ? -1.0f : 0.0f)) : 0.0f;
        float4 d = make_float4(0.f, 0.f, 0.f, 0.f);
        if (pos && v) d = compute_deltas(ab, s_gt[bg], stdev);
        ((float4*)(out + A))[ai] = d;
    }
    __syncthreads();
    if (tid < G && s_key[tid] != 0ULL) atomicMax(&gkey[tid], s_key[tid]);
    if (tid == 0 && s_cnt > 0) atomicAdd(cnt, s_cnt);
    __threadfence();
    if (tid == 0) {
        unsigned prev = atomicAdd(done, 1u);
        s_islast = (prev == gridDim.x - 1);
        s_cnt = 0;
    }
    __syncthreads();
    if (!s_islast) return;
    __threadfence();
    if (tid < G && s_crowdf[tid] == 0.0f) {
        unsigned long long key = gkey[tid];
        int w;
        if (key != 0ULL) w = (int)(~(unsigned)(key & 0xFFFFFFFFull));
        else { w = 0; for (int i = 0; i < A; ++i) { if (valid[i] != 0) { w = i; break; } } }
        if (valid[w] != 0) {
            float old = atomicExch(out + w, 1.0f);
            if (old != 1.0f) {
                float4 ab2 = anchors[w];
                float a2 = (ab2.z - ab2.x) * (ab2.w - ab2.y);
                float b2 = -2.0f; int g2 = 0;
                for (int g = 0; g < G; ++g) {
                    float iou = iou_of(ab2, a2, s_gt[g]);
                    float eff = (s_crowdf[g] != 0.0f) ? -1.0f : iou;
                    if (eff > b2) { b2 = eff; g2 = g; }
                }
                ((float4*)(out + A))[w] = compute_deltas(ab2, s_gt[g2], stdev);
                atomicAdd(&s_cnt, 1);
            }
        }
    }
    __syncthreads();
    if (tid == 0) out[(size_t)5 * A] = (float)(*cnt + s_cnt);
}

extern "C" void kernel_launch(void* const* d_in, const int* in_sizes, int n_in,
                              void* d_out, int out_size, void* d_ws, size_t ws_size,
                              hipStream_t stream) {
    const float4* anchors = (const float4*)d_in[0];
    const int* valid      = (const int*)d_in[1];   // jnp bool -> int32 per element
    const int* cls        = (const int*)d_in[2];
    const float4* gt      = (const float4*)d_in[3];
    const float* stdev    = (const float*)d_in[4];
    float* out            = (float*)d_out;

    const int A = in_sizes[0] / 4;
    const int G = in_sizes[2];                     // 256
    const int nb4 = (A + 127) / 128;               // 2046 blocks (128 anchors/block)

    const size_t akey_bytes  = (size_t)A * 8;
    const size_t shard_bytes = (size_t)G * SHARDS * 8;
    const size_t pcnt_bytes  = (size_t)nb4 * 4;
    const size_t fv_bytes    = (size_t)nb4 * 4;
    const size_t needed = akey_bytes + shard_bytes + pcnt_bytes + fv_bytes;

    if (ws_size >= needed && G <= GMAX) {
        char* p = (char*)d_ws;
        unsigned long long* akey  = (unsigned long long*)p;          p += akey_bytes;
        unsigned long long* gkeyS = (unsigned long long*)p;          p += shard_bytes;
        int* pcount               = (int*)p;                         p += pcnt_bytes;
        int* fvmin                = (int*)p;

        rpn_main5<<<nb4, 256, 0, stream>>>(anchors, valid, cls, gt, stdev, out,
                                           akey, gkeyS, pcount, fvmin, A, G);
        rpn_finalize2<<<1, 1024, 0, stream>>>(anchors, valid, cls, gt, stdev, out,
                                              akey, gkeyS, pcount, fvmin, nb4, A, G);
    } else {
        const int nb = (A + 255) / 256;
        unsigned long long* gkey = (unsigned long long*)d_ws;
        unsigned* done = (unsigned*)((char*)d_ws + 2048);
        int* cnt       = (int*)((char*)d_ws + 2052);
        hipMemsetAsync(d_ws, 0, 2056, stream);
        rpn_fused<<<nb, 256, 0, stream>>>(anchors, valid, cls, gt, stdev, out,
                                          gkey, done, cnt, A, G);
    }
}